// Round 4
// baseline (363.565 us; speedup 1.0000x reference)
//
#include <hip/hip_runtime.h>
#include <math.h>

// Problem constants (from reference): B=64, C=64, L=8192, fp32.
#define BB 64
#define CC 64
#define LL 8192
#define EPS_F 1.1920928955078125e-07f  // np.finfo(np.float32).eps

#define GROUPS 32                // blocks per batch
#define ROWS_PER_BLK 2           // CC / GROUPS
#define NBLK (BB * GROUPS)       // 2048 blocks = 8/CU x 256 CU (machine-filling)
#define ROW4 (LL / 4)            // 2048 float4 per row

typedef float f4 __attribute__((ext_vector_type(4)));
typedef int   i4 __attribute__((ext_vector_type(4)));

union pk64 { unsigned long long u; struct { float x, y; } f; };

// d_ws layout (first 1280 B zeroed by hipMemsetAsync each launch):
//   [0,    512)  u64   ready[64]  packed {mean, inv}; 0 == not ready (inv>0)
//   [512,  768)  int   cnt[64]    arrival counters (ACQ_REL incremented)
//   [768, 1024)  float sums[64]   atomicAdd accumulated
//   [1024,1280)  float sqs[64]    atomicAdd accumulated

// ---------------------------------------------------------------------------
// One-pass, MLP-maximized. Block blk = b*32 + t owns rows 2t, 2t+1 of batch b.
// Round-3 post-mortem: VGPR=28 proved the compiler sank loads into consumers
// (~4 in flight/wave); 12 waves/CU x 4 x 16B / 900cyc = the measured 1.5 TB/s.
// Fixes: (a) 2048 blocks @ <=64 VGPR -> 32 waves/CU; (b) named-register
// 8-load batches pinned by sched_barrier(0) so loads issue before consumers.
// ---------------------------------------------------------------------------
__global__ __launch_bounds__(256, 8) void tln_onepass(
    const float* __restrict__ data,
    const int*   __restrict__ zero_pos,
    const i4*    __restrict__ idxes,
    unsigned long long* __restrict__ ready,     // [64]
    int*                __restrict__ cnt,       // [64]
    float*              __restrict__ sums,      // [64]
    float*              __restrict__ sqs,       // [64]
    f4*          __restrict__ out4,
    f4*          __restrict__ out_idx,
    float*       __restrict__ out_zp)
{
    const int blk = blockIdx.x;
    const int tid = threadIdx.x;           // 0..255
    const int b   = blk >> 5;
    const int t   = blk & 31;
    const int zp  = zero_pos[b];
    const int nv  = zp >> 2;               // full float4's per row
    const int rem = zp & 3;

    const float* base = data + ((size_t)b * CC + (size_t)t * ROWS_PER_BLK) * LL;
    const f4* r0 = (const f4*)(base);
    const f4* r1 = (const f4*)(base + (size_t)LL);

    // ---- Phase 1: prefix partial, 8 loads in flight (2 rows x 4 steps) ----
    float s0 = 0.f, s1 = 0.f, q0 = 0.f, q1 = 0.f;
    const int nfull = nv & ~1023;          // full 8-load batches (uniform)
    for (int i = tid; i < nfull; i += 1024) {
        f4 a0 = r0[i], a1 = r0[i + 256], a2 = r0[i + 512], a3 = r0[i + 768];
        f4 c0 = r1[i], c1 = r1[i + 256], c2 = r1[i + 512], c3 = r1[i + 768];
        __builtin_amdgcn_sched_barrier(0);  // pin: all 8 issued before use
        s0 += a0.x+a0.y+a0.z+a0.w;  q0 += a0.x*a0.x+a0.y*a0.y+a0.z*a0.z+a0.w*a0.w;
        s0 += a1.x+a1.y+a1.z+a1.w;  q0 += a1.x*a1.x+a1.y*a1.y+a1.z*a1.z+a1.w*a1.w;
        s0 += a2.x+a2.y+a2.z+a2.w;  q0 += a2.x*a2.x+a2.y*a2.y+a2.z*a2.z+a2.w*a2.w;
        s0 += a3.x+a3.y+a3.z+a3.w;  q0 += a3.x*a3.x+a3.y*a3.y+a3.z*a3.z+a3.w*a3.w;
        s1 += c0.x+c0.y+c0.z+c0.w;  q1 += c0.x*c0.x+c0.y*c0.y+c0.z*c0.z+c0.w*c0.w;
        s1 += c1.x+c1.y+c1.z+c1.w;  q1 += c1.x*c1.x+c1.y*c1.y+c1.z*c1.z+c1.w*c1.w;
        s1 += c2.x+c2.y+c2.z+c2.w;  q1 += c2.x*c2.x+c2.y*c2.y+c2.z*c2.z+c2.w*c2.w;
        s1 += c3.x+c3.y+c3.z+c3.w;  q1 += c3.x*c3.x+c3.y*c3.y+c3.z*c3.z+c3.w*c3.w;
    }
    for (int i = nfull + tid; i < nv; i += 256) {   // remainder f4's
        f4 a = r0[i], c = r1[i];
        s0 += a.x+a.y+a.z+a.w;  q0 += a.x*a.x+a.y*a.y+a.z*a.z+a.w*a.w;
        s1 += c.x+c.y+c.z+c.w;  q1 += c.x*c.x+c.y*c.y+c.z*c.z+c.w*c.w;
    }
    if (rem && tid < 8) {                  // scalar tail: row=tid>>2, e=tid&3
        const int rr = tid >> 2, e = tid & 3;
        if (e < rem) {
            float v = base[(size_t)rr * LL + nv * 4 + e];
            s0 += v; q0 += v * v;
        }
    }
    float sum = s0 + s1;
    float sq  = q0 + q1;

    // block reduce: wave shfl + LDS across 4 waves
    #pragma unroll
    for (int off = 32; off > 0; off >>= 1) {
        sum += __shfl_down(sum, off);
        sq  += __shfl_down(sq, off);
    }
    __shared__ float lsum[4], lsq[4];
    __shared__ float s_m, s_inv;
    const int wave = tid >> 6;
    const int lane = tid & 63;
    if (lane == 0) { lsum[wave] = sum; lsq[wave] = sq; }
    __syncthreads();
    if (tid == 0) {
        float bs = lsum[0] + lsum[1] + lsum[2] + lsum[3];
        float bq = lsq[0]  + lsq[1]  + lsq[2]  + lsq[3];
        atomicAdd(&sums[b], bs);           // device-scope by default
        atomicAdd(&sqs[b],  bq);
        const int old = __hip_atomic_fetch_add(&cnt[b], 1, __ATOMIC_ACQ_REL,
                                               __HIP_MEMORY_SCOPE_AGENT);
        if (old == GROUPS - 1) {           // last arriver: compute + publish
            float S = __hip_atomic_load(&sums[b], __ATOMIC_RELAXED,
                                        __HIP_MEMORY_SCOPE_AGENT);
            float Q = __hip_atomic_load(&sqs[b], __ATOMIC_RELAXED,
                                        __HIP_MEMORY_SCOPE_AGENT);
            const float cf   = (float)CC * (float)zp;
            const float mean = S / cf;
            const float var  = (Q - cf * mean * mean) / (cf - 1.0f);
            pk64 o;
            o.f.x = mean;
            o.f.y = 1.0f / (sqrtf(var) + EPS_F);   // > 0 always => u64 != 0
            __hip_atomic_store(&ready[b], o.u, __ATOMIC_RELEASE,
                               __HIP_MEMORY_SCOPE_AGENT);
        }
    }

    // ---- Overlap window: idx conversion (64 i4 per block) + zp out ----
    if (tid < 64) {
        const int ii = blk * 64 + tid;     // covers exactly B*L/4 = 131072
        i4 v = idxes[ii];
        f4 o = __builtin_convertvector(v, f4);
        __builtin_nontemporal_store(o, out_idx + ii);
    }
    if (blk == 0 && tid < BB) out_zp[tid] = (float)zero_pos[tid];

    // ---- Gate: relaxed-load spin; loaded value IS {mean, inv} ----
    if (tid == 0) {
        pk64 r_;
        for (;;) {
            r_.u = __hip_atomic_load(&ready[b], __ATOMIC_RELAXED,
                                     __HIP_MEMORY_SCOPE_AGENT);
            if (r_.u != 0ull) break;
            __builtin_amdgcn_s_sleep(8);
        }
        s_m = r_.f.x; s_inv = r_.f.y;
    }
    __syncthreads();
    const float m = s_m, inv = s_inv;

    // ---- Phase 2: normalize own 2 rows, 8 named loads in flight, NT stores --
    const size_t obase = ((size_t)b * CC + (size_t)t * ROWS_PER_BLK) * ROW4;
    #pragma unroll
    for (int r = 0; r < ROWS_PER_BLK; ++r) {
        const f4* rp = (const f4*)(base + (size_t)r * LL);
        f4* op = out4 + obase + (size_t)r * ROW4;
        f4 v0 = rp[tid];
        f4 v1 = rp[tid +  256];
        f4 v2 = rp[tid +  512];
        f4 v3 = rp[tid +  768];
        f4 v4 = rp[tid + 1024];
        f4 v5 = rp[tid + 1280];
        f4 v6 = rp[tid + 1536];
        f4 v7 = rp[tid + 1792];
        __builtin_amdgcn_sched_barrier(0);  // pin: all 8 issued before stores
        __builtin_nontemporal_store((v0 - m) * inv, op + tid);
        __builtin_nontemporal_store((v1 - m) * inv, op + tid +  256);
        __builtin_nontemporal_store((v2 - m) * inv, op + tid +  512);
        __builtin_nontemporal_store((v3 - m) * inv, op + tid +  768);
        __builtin_nontemporal_store((v4 - m) * inv, op + tid + 1024);
        __builtin_nontemporal_store((v5 - m) * inv, op + tid + 1280);
        __builtin_nontemporal_store((v6 - m) * inv, op + tid + 1536);
        __builtin_nontemporal_store((v7 - m) * inv, op + tid + 1792);
    }
}

extern "C" void kernel_launch(void* const* d_in, const int* in_sizes, int n_in,
                              void* d_out, int out_size, void* d_ws, size_t ws_size,
                              hipStream_t stream) {
    const float* data    = (const float*)d_in[0];
    const int* idxes     = (const int*)d_in[1];
    const int* zero_pos  = (const int*)d_in[2];

    float* out_data = (float*)d_out;                        // B*C*L
    float* out_idx  = out_data + (size_t)BB * CC * LL;      // B*L
    float* out_zp   = out_idx + (size_t)BB * LL;            // B

    unsigned long long* ready = (unsigned long long*)d_ws;          // 512 B
    int*   cnt  = (int*)((char*)d_ws + 512);                        // 256 B
    float* sums = (float*)((char*)d_ws + 768);                      // 256 B
    float* sqs  = (float*)((char*)d_ws + 1024);                     // 256 B

    hipMemsetAsync(d_ws, 0, 1280, stream);

    tln_onepass<<<NBLK, 256, 0, stream>>>(
        data, zero_pos, (const i4*)idxes, ready, cnt, sums, sqs,
        (f4*)out_data, (f4*)out_idx, out_zp);
}

// Round 5
// 244.711 us; speedup vs baseline: 1.4857x; 1.4857x over previous
//
#include <hip/hip_runtime.h>
#include <math.h>

// Problem constants (from reference): B=64, C=64, L=8192, fp32.
#define BB 64
#define CC 64
#define LL 8192
#define EPS_F 1.1920928955078125e-07f  // np.finfo(np.float32).eps
#define SPLITS 32                       // stats blocks per batch

// Normalize decomposition: each block handles 2048 float4 (8 iters x 256 thr)
#define NORM_BLOCKS_PER_B 64            // (C*L/4) / 2048 = 64
#define NB_NORM (BB * NORM_BLOCKS_PER_B) // 4096 normalize blocks
#define NB_AUX  512                      // B*L/4/256 idx-convert blocks

typedef float f4 __attribute__((ext_vector_type(4)));
typedef int   i4 __attribute__((ext_vector_type(4)));

// d_ws layout: partials[b][s] = float2{sum, sumsq}, 64*32 slots (16 KB).
// Every slot is written by tln_stats -> no zeroing pass, no atomics.

// ---------------------------------------------------------------------------
// Kernel 1: per-(b,s) partial {sum, sumsq} over prefix data[b, :, :zp[b]].
// Grid (B, SPLITS) x 256. Block (b,s) handles rows c = s, s+32.
// 2 row-streams x 2-way unroll = 4 independent loads per window, separate
// accumulators (r0-r4 lesson: TLP structure + modest ILP; no VGPR cap).
// Regular (caching) loads on purpose: they warm L2/L3 with the prefix,
// which kernel 2 re-reads; kernel 2's stores are non-temporal.
// ---------------------------------------------------------------------------
__global__ __launch_bounds__(256) void tln_stats(const float* __restrict__ data,
                          const int* __restrict__ zero_pos,
                          float2* __restrict__ partials) {
    const int b = blockIdx.x;
    const int s = blockIdx.y;
    const int tid = threadIdx.x;           // 0..255
    const int zp = zero_pos[b];
    const int nv = zp >> 2;                // full float4's per row
    const float* base = data + (size_t)b * CC * LL;
    const float* row0 = base + (size_t)s * LL;
    const float* row1 = base + (size_t)(s + SPLITS) * LL;
    const f4* p0 = (const f4*)row0;
    const f4* p1 = (const f4*)row1;

    float s0 = 0.f, s1 = 0.f, s2 = 0.f, s3 = 0.f;
    float q0 = 0.f, q1 = 0.f, q2 = 0.f, q3 = 0.f;
    int i = tid;
    for (; i + 256 < nv; i += 512) {       // 4 independent loads per window
        f4 a = p0[i], c = p0[i + 256], d = p1[i], e = p1[i + 256];
        s0 += a.x+a.y+a.z+a.w;  q0 += a.x*a.x+a.y*a.y+a.z*a.z+a.w*a.w;
        s1 += c.x+c.y+c.z+c.w;  q1 += c.x*c.x+c.y*c.y+c.z*c.z+c.w*c.w;
        s2 += d.x+d.y+d.z+d.w;  q2 += d.x*d.x+d.y*d.y+d.z*d.z+d.w*d.w;
        s3 += e.x+e.y+e.z+e.w;  q3 += e.x*e.x+e.y*e.y+e.z*e.z+e.w*e.w;
    }
    for (; i < nv; i += 256) {             // remainder float4's
        f4 a = p0[i], d = p1[i];
        s0 += a.x+a.y+a.z+a.w;  q0 += a.x*a.x+a.y*a.y+a.z*a.z+a.w*a.w;
        s2 += d.x+d.y+d.z+d.w;  q2 += d.x*d.x+d.y*d.y+d.z*d.z+d.w*d.w;
    }
    // scalar tail (at most 3 elements per row)
    for (int l = (nv << 2) + tid; l < zp; l += 256) {
        float v0 = row0[l], v1 = row1[l];
        s0 += v0; q0 += v0 * v0;
        s2 += v1; q2 += v1 * v1;
    }
    float sum = (s0 + s1) + (s2 + s3);
    float sq  = (q0 + q1) + (q2 + q3);

    // wave-64 reduce, then cross-wave via LDS
    #pragma unroll
    for (int off = 32; off > 0; off >>= 1) {
        sum += __shfl_down(sum, off);
        sq  += __shfl_down(sq, off);
    }
    __shared__ float lsum[4], lsq[4];
    const int wave = tid >> 6;
    const int lane = tid & 63;
    if (lane == 0) { lsum[wave] = sum; lsq[wave] = sq; }
    __syncthreads();
    if (tid == 0) {
        float2 p;
        p.x = lsum[0] + lsum[1] + lsum[2] + lsum[3];
        p.y = lsq[0] + lsq[1] + lsq[2] + lsq[3];
        partials[b * SPLITS + s] = p;
    }
}

// ---------------------------------------------------------------------------
// Kernel 2 (fused): blocks [0, NB_NORM) normalize the slab; each block does
// 2048 consecutive float4 (8 per thread), recomputing mean/inv from the 32
// L2-hot partials with an all-lane shfl_xor butterfly (no LDS, no barrier).
// Normalize loop is 2-stage software-pipelined: load k+1 issues before the
// NT store of k, so the read stream never stalls behind the write stream.
// Blocks [NB_NORM, NB_NORM+NB_AUX) convert idxes->float and write zero_pos.
// ---------------------------------------------------------------------------
__global__ __launch_bounds__(256) void tln_fused(const f4* __restrict__ data4,
                          const float2* __restrict__ partials,
                          const int* __restrict__ zero_pos,
                          const i4* __restrict__ idxes,
                          f4* __restrict__ out4,
                          f4* __restrict__ out_idx,
                          float* __restrict__ out_zp) {
    const int blk = blockIdx.x;
    const int tid = threadIdx.x;

    if (blk < NB_NORM) {
        const int b = blk >> 6;            // NORM_BLOCKS_PER_B = 64
        const int t = blk & 63;
        const int lane = tid & 63;

        // every lane loads one of the 32 partials (halves duplicate), then a
        // 5-step xor-butterfly gives every lane the full {sum, sumsq}
        float2 p = partials[(b << 5) + (lane & 31)];
        float s_ = p.x, q_ = p.y;
        #pragma unroll
        for (int off = 16; off > 0; off >>= 1) {
            s_ += __shfl_xor(s_, off);
            q_ += __shfl_xor(q_, off);
        }
        const float cnt  = (float)CC * (float)zero_pos[b];
        const float mean = s_ / cnt;
        const float var  = (q_ - cnt * mean * mean) / (cnt - 1.0f);
        const float inv  = 1.0f / (sqrtf(var) + EPS_F);

        // b*131072 + t*2048 + tid  (disjoint bit fields)
        const size_t base = ((size_t)b << 17) | ((size_t)t << 11) | (size_t)tid;
        f4 cur = data4[base];
        #pragma unroll
        for (int k = 0; k < 7; ++k) {
            f4 nxt = data4[base + (size_t)((k + 1) << 8)];   // issue next load
            __builtin_nontemporal_store((cur - mean) * inv,  // then store cur
                                        out4 + base + (size_t)(k << 8));
            cur = nxt;
        }
        __builtin_nontemporal_store((cur - mean) * inv, out4 + base + (size_t)(7 << 8));
    } else {
        const int j = blk - NB_NORM;
        const int i = j * 256 + tid;       // < 131072
        i4 v = idxes[i];
        f4 o = __builtin_convertvector(v, f4);
        __builtin_nontemporal_store(o, out_idx + i);
        if (j == 0 && tid < BB) out_zp[tid] = (float)zero_pos[tid];
    }
}

extern "C" void kernel_launch(void* const* d_in, const int* in_sizes, int n_in,
                              void* d_out, int out_size, void* d_ws, size_t ws_size,
                              hipStream_t stream) {
    const float* data    = (const float*)d_in[0];
    const int* idxes     = (const int*)d_in[1];
    const int* zero_pos  = (const int*)d_in[2];

    float2* partials = (float2*)d_ws;       // B*SPLITS slots, all overwritten

    float* out_data = (float*)d_out;                        // B*C*L
    float* out_idx  = out_data + (size_t)BB * CC * LL;      // B*L
    float* out_zp   = out_idx + (size_t)BB * LL;            // B

    tln_stats<<<dim3(BB, SPLITS), 256, 0, stream>>>(data, zero_pos, partials);

    tln_fused<<<NB_NORM + NB_AUX, 256, 0, stream>>>(
        (const f4*)data, partials, zero_pos, (const i4*)idxes,
        (f4*)out_data, (f4*)out_idx, out_zp);
}

// Round 6
// 241.425 us; speedup vs baseline: 1.5059x; 1.0136x over previous
//
#include <hip/hip_runtime.h>
#include <math.h>

// Problem constants (from reference): B=64, C=64, L=8192, fp32.
#define BB 64
#define CC 64
#define LL 8192
#define EPS_F 1.1920928955078125e-07f  // np.finfo(np.float32).eps

#define NB_STAT (BB * CC)               // 4096 stats blocks: one row each
#define NB_AUX  512                     // B*L/4/256 idx-convert blocks
#define ROW4 (LL / 4)                   // 2048 float4 per row

// Fused normalize: 4 f4/thread, 1024 f4/block -> 8192 blocks (128 per batch)
#define NB_NORM 8192

typedef float f4 __attribute__((ext_vector_type(4)));
typedef int   i4 __attribute__((ext_vector_type(4)));

// d_ws layout: partials[b][c] = float2{sum, sumsq}, 64*64 slots (32 KB).
// Every slot is written by tln_stats -> no zeroing pass, no atomics.

// ---------------------------------------------------------------------------
// Kernel 1: blocks [0, NB_STAT) compute per-ROW partial {sum, sumsq} over
// data[b, c, :zp[b]].  One row per block (r5 post-mortem: 8 resident
// zp-proportional blocks/CU left ~1.6x imbalance; 16/CU + backfill halves
// the variance).  4 independent loads per window, separate accumulators.
// Caching loads on purpose: warm L2/L3 for kernel 2's re-read.
// Blocks [NB_STAT, NB_STAT+NB_AUX) do the idx->float conversion here, where
// the write pipe is otherwise idle (overlaps the read-only stats stream).
// ---------------------------------------------------------------------------
__global__ __launch_bounds__(256) void tln_stats(const float* __restrict__ data,
                          const int* __restrict__ zero_pos,
                          const i4* __restrict__ idxes,
                          float2* __restrict__ partials,
                          f4* __restrict__ out_idx,
                          float* __restrict__ out_zp) {
    const int blk = blockIdx.x;
    const int tid = threadIdx.x;           // 0..255

    if (blk < NB_STAT) {
        const int b = blk >> 6;
        const int c = blk & 63;
        const int zp = zero_pos[b];
        const int nv = zp >> 2;            // full float4's in this row
        const float* rowp = data + ((size_t)b * CC + c) * LL;
        const f4* p = (const f4*)rowp;     // L=8192 -> 16B aligned

        float s0 = 0.f, s1 = 0.f, s2 = 0.f, s3 = 0.f;
        float q0 = 0.f, q1 = 0.f, q2 = 0.f, q3 = 0.f;
        int i = tid;
        for (; i + 768 < nv; i += 1024) {  // 4 independent loads per window
            f4 a = p[i], d = p[i + 256], e = p[i + 512], g = p[i + 768];
            s0 += a.x+a.y+a.z+a.w;  q0 += a.x*a.x+a.y*a.y+a.z*a.z+a.w*a.w;
            s1 += d.x+d.y+d.z+d.w;  q1 += d.x*d.x+d.y*d.y+d.z*d.z+d.w*d.w;
            s2 += e.x+e.y+e.z+e.w;  q2 += e.x*e.x+e.y*e.y+e.z*e.z+e.w*e.w;
            s3 += g.x+g.y+g.z+g.w;  q3 += g.x*g.x+g.y*g.y+g.z*g.z+g.w*g.w;
        }
        for (; i < nv; i += 256) {         // remainder float4's
            f4 a = p[i];
            s0 += a.x+a.y+a.z+a.w;  q0 += a.x*a.x+a.y*a.y+a.z*a.z+a.w*a.w;
        }
        {                                   // scalar tail: at most 3 elements
            const int l = (nv << 2) + tid;
            if (l < zp) {
                float v = rowp[l];
                s0 += v; q0 += v * v;
            }
        }
        float sum = (s0 + s1) + (s2 + s3);
        float sq  = (q0 + q1) + (q2 + q3);

        // wave-64 reduce, then cross-wave via LDS
        #pragma unroll
        for (int off = 32; off > 0; off >>= 1) {
            sum += __shfl_down(sum, off);
            sq  += __shfl_down(sq, off);
        }
        __shared__ float lsum[4], lsq[4];
        const int wave = tid >> 6;
        const int lane = tid & 63;
        if (lane == 0) { lsum[wave] = sum; lsq[wave] = sq; }
        __syncthreads();
        if (tid == 0) {
            float2 pr;
            pr.x = lsum[0] + lsum[1] + lsum[2] + lsum[3];
            pr.y = lsq[0] + lsq[1] + lsq[2] + lsq[3];
            partials[blk] = pr;            // partials[b*64 + c]
        }
    } else {
        const int j = blk - NB_STAT;
        const int ii = j * 256 + tid;      // < 131072 = B*L/4
        i4 v = idxes[ii];
        f4 o = __builtin_convertvector(v, f4);
        __builtin_nontemporal_store(o, out_idx + ii);
        if (j == 0 && tid < BB) out_zp[tid] = (float)zero_pos[tid];
    }
}

// ---------------------------------------------------------------------------
// Kernel 2: pure normalize. 8192 blocks x 1024 f4 (4 per thread) -- finer
// backfill granularity than r5's 4096x8 (TLP is the proven lever here).
// Each block recomputes mean/inv from its batch's 64 L2-hot row-partials
// with a 6-step all-lane shfl_xor butterfly (no LDS, no barrier).
// Depth-2 software pipeline: load k+1 issues before the NT store of k.
// NT stores keep the stats-warmed prefix resident in L3.
// ---------------------------------------------------------------------------
__global__ __launch_bounds__(256) void tln_fused(const f4* __restrict__ data4,
                          const float2* __restrict__ partials,
                          const int* __restrict__ zero_pos,
                          f4* __restrict__ out4) {
    const int blk = blockIdx.x;
    const int tid = threadIdx.x;
    const int b = blk >> 7;                // 128 blocks per batch
    const int t = blk & 127;
    const int lane = tid & 63;

    // one partial per lane, 6-step butterfly -> every lane has {S, Q}
    float2 p = partials[(b << 6) + lane];
    float s_ = p.x, q_ = p.y;
    #pragma unroll
    for (int off = 32; off > 0; off >>= 1) {
        s_ += __shfl_xor(s_, off);
        q_ += __shfl_xor(q_, off);
    }
    const float cnt  = (float)CC * (float)zero_pos[b];
    const float mean = s_ / cnt;
    const float var  = (q_ - cnt * mean * mean) / (cnt - 1.0f);
    const float inv  = 1.0f / (sqrtf(var) + EPS_F);

    // b*131072 + t*1024 + tid  (disjoint bit fields)
    const size_t base = ((size_t)b << 17) | ((size_t)t << 10) | (size_t)tid;
    f4 cur = data4[base];
    #pragma unroll
    for (int k = 0; k < 3; ++k) {
        f4 nxt = data4[base + (size_t)((k + 1) << 8)];   // issue next load
        __builtin_nontemporal_store((cur - mean) * inv,  // then store cur
                                    out4 + base + (size_t)(k << 8));
        cur = nxt;
    }
    __builtin_nontemporal_store((cur - mean) * inv, out4 + base + (size_t)(3 << 8));
}

extern "C" void kernel_launch(void* const* d_in, const int* in_sizes, int n_in,
                              void* d_out, int out_size, void* d_ws, size_t ws_size,
                              hipStream_t stream) {
    const float* data    = (const float*)d_in[0];
    const int* idxes     = (const int*)d_in[1];
    const int* zero_pos  = (const int*)d_in[2];

    float2* partials = (float2*)d_ws;       // B*C slots (32 KB), all overwritten

    float* out_data = (float*)d_out;                        // B*C*L
    float* out_idx  = out_data + (size_t)BB * CC * LL;      // B*L
    float* out_zp   = out_idx + (size_t)BB * LL;            // B

    tln_stats<<<NB_STAT + NB_AUX, 256, 0, stream>>>(
        data, zero_pos, (const i4*)idxes, partials, (f4*)out_idx, out_zp);

    tln_fused<<<NB_NORM, 256, 0, stream>>>(
        (const f4*)data, partials, zero_pos, (f4*)out_data);
}